// Round 1
// baseline (295.900 us; speedup 1.0000x reference)
//
#include <hip/hip_runtime.h>
#include <hip/hip_bf16.h>
#include <stdint.h>

typedef __bf16 bf16;
typedef __bf16 bf16x8 __attribute__((ext_vector_type(8)));
typedef __bf16 bf16x4 __attribute__((ext_vector_type(4)));
typedef float f32x4 __attribute__((ext_vector_type(4)));

#define BB 32
#define TT 2048
#define DD 1024
#define HH 128
#define SCALE 0.08838834764831845f   // H^-0.5
#define LOG2E 1.4426950408889634f

__device__ __forceinline__ void gl_lds16(const bf16* g, bf16* l) {
  __builtin_amdgcn_global_load_lds((__attribute__((address_space(1))) const void*)g,
                                   (__attribute__((address_space(3))) void*)l,
                                   16, 0, 0);
}

// ---------------- kernel 0: Wt[mat][h][d] = W[d][h] (fp32 -> bf16) -------------
__global__ __launch_bounds__(256) void prep_w(const float* __restrict__ Wk,
                                              const float* __restrict__ Wq,
                                              const float* __restrict__ Wv,
                                              bf16* __restrict__ Wt) {
  int tid = blockIdx.x * 256 + threadIdx.x;   // 0..49151
  int mat = tid >> 14;
  int r = tid & 16383;
  int h = r & 127;
  int d0 = (r >> 7) << 3;
  const float* W = (mat == 0) ? Wk : (mat == 1) ? Wq : Wv;
  bf16x8 v;
#pragma unroll
  for (int i = 0; i < 8; ++i) v[i] = (bf16)W[(size_t)(d0 + i) * HH + h];
  *(bf16x8*)(Wt + ((size_t)mat * HH + h) * DD + d0) = v;
}

// ---------------- kernel 1: fused QKV projection GEMM (bf16 MFMA) --------------
// grid = 512 mtiles * 3 mats; block 256 = 4 waves (2x2), tile 128x128, BK=32
__global__ __launch_bounds__(256) void qkv_proj(
    const float* __restrict__ x, const bf16* __restrict__ Wt,
    const float* __restrict__ bk, const float* __restrict__ bq,
    const float* __restrict__ bv,
    bf16* __restrict__ kb, bf16* __restrict__ qb, bf16* __restrict__ vb) {
  const int bid = blockIdx.x;
  const int mat = bid % 3;
  const int mtile = bid / 3;
  const int tid = threadIdx.x;
  const int lane = tid & 63;
  const int w = tid >> 6;
  const int wr = w >> 1, wc = w & 1;
  const int l15 = lane & 15, l4 = lane >> 4;

  __shared__ __attribute__((aligned(16))) bf16 As[2][128][40];  // pad 40 -> ~2-way banks
  __shared__ __attribute__((aligned(16))) bf16 Bs[2][128][40];

  const size_t row0 = (size_t)mtile * 128;
  const bf16* Wm = Wt + (size_t)mat * HH * DD;
  const float* bias = (mat == 0) ? bk : (mat == 1) ? bq : bv;
  bf16* outp = (mat == 0) ? kb : (mat == 1) ? qb : vb;

  const int ar = tid >> 3, ac = (tid & 7) * 4;   // A stage: 8 thr/row
  const int br = tid >> 2, bc = (tid & 3) * 8;   // B stage: 4 thr/row

  f32x4 acc[4][4];
#pragma unroll
  for (int i = 0; i < 4; ++i)
#pragma unroll
    for (int j = 0; j < 4; ++j) acc[i][j] = f32x4{0.f, 0.f, 0.f, 0.f};

  auto stage = [&](int buf, int k0) {
#pragma unroll
    for (int p = 0; p < 4; ++p) {
      int r = p * 32 + ar;
      f32x4 a = *(const f32x4*)(x + (row0 + r) * DD + k0 + ac);
      bf16x4 t;
#pragma unroll
      for (int i = 0; i < 4; ++i) t[i] = (bf16)a[i];
      *(bf16x4*)&As[buf][r][ac] = t;
    }
#pragma unroll
    for (int p = 0; p < 2; ++p) {
      int r = p * 64 + br;
      bf16x8 bv8 = *(const bf16x8*)(Wm + (size_t)r * DD + k0 + bc);
      *(bf16x8*)&Bs[buf][r][bc] = bv8;
    }
  };

  stage(0, 0);
  __syncthreads();

  for (int k0 = 0; k0 < DD; k0 += 32) {
    const int cur = (k0 >> 5) & 1;
    if (k0 + 32 < DD) stage(cur ^ 1, k0 + 32);

    bf16x8 af[4], bfr[4];
#pragma unroll
    for (int f = 0; f < 4; ++f)
      af[f] = *(const bf16x8*)&As[cur][wr * 64 + f * 16 + l15][l4 * 8];
#pragma unroll
    for (int f = 0; f < 4; ++f)
      bfr[f] = *(const bf16x8*)&Bs[cur][wc * 64 + f * 16 + l15][l4 * 8];
#pragma unroll
    for (int i = 0; i < 4; ++i)
#pragma unroll
      for (int j = 0; j < 4; ++j)
        acc[i][j] = __builtin_amdgcn_mfma_f32_16x16x32_bf16(af[i], bfr[j],
                                                            acc[i][j], 0, 0, 0);
    __syncthreads();
  }

  float bvv[4];
#pragma unroll
  for (int f = 0; f < 4; ++f) bvv[f] = bias[wc * 64 + f * 16 + l15];
#pragma unroll
  for (int i = 0; i < 4; ++i)
#pragma unroll
    for (int j = 0; j < 4; ++j) {
      int col = wc * 64 + j * 16 + l15;
#pragma unroll
      for (int e = 0; e < 4; ++e) {
        int row = wr * 64 + i * 16 + l4 * 4 + e;
        outp[(row0 + row) * HH + col] = (bf16)(acc[i][j][e] + bvv[j]);
      }
    }
}

// ---------------- kernel 2: Vt[b][h][t] = v[b][t][h] ---------------------------
__global__ __launch_bounds__(256) void transpose_v(const bf16* __restrict__ vb,
                                                   bf16* __restrict__ Vt) {
  __shared__ __attribute__((aligned(16))) bf16 Ls[128 * 128];
  const int bid = blockIdx.x;
  const int b = bid >> 4;
  const int t0 = (bid & 15) << 7;
  const int tid = threadIdx.x;
  const int r = tid >> 1, half = tid & 1;

  const bf16* src = vb + ((size_t)b * TT + t0 + r) * HH + half * 64;
#pragma unroll
  for (int i = 0; i < 8; ++i) {
    int c = half * 8 + i;              // 16B chunk within the 128-elem row
    int cs = c ^ (r & 7);              // XOR swizzle
    bf16x8 v = *(const bf16x8*)(src + i * 8);
    *(bf16x8*)&Ls[r * 128 + cs * 8] = v;
  }
  __syncthreads();
  const int h = tid >> 1;
  bf16 tmp[64];
#pragma unroll
  for (int i = 0; i < 64; ++i) {
    int t = half * 64 + i;
    tmp[i] = Ls[t * 128 + (((h >> 3) ^ (t & 7)) * 8) + (h & 7)];
  }
  bf16* dst = Vt + ((size_t)b * HH + h) * TT + t0 + half * 64;
#pragma unroll
  for (int i = 0; i < 8; ++i)
    *(bf16x8*)(dst + i * 8) = *(bf16x8*)&tmp[i * 8];
}

// ---------------- kernel 3: fused causal flash attention -----------------------
// quirk: scores[t][s] = k[t] . q[s]  -> k rows are the softmax rows.
// grid 512 = 32 batches * 16 k-tiles(128 rows), work-balanced ordering.
// block 256 = 4 waves * 32 rows. s-tiles of 64.
__global__ __launch_bounds__(256) void attn(const bf16* __restrict__ kb,
                                            const bf16* __restrict__ qb,
                                            const bf16* __restrict__ Vt,
                                            float* __restrict__ out) {
  const int bid = blockIdx.x;
  const int g = bid >> 5;
  const int b = bid & 31;
  const int tile = (g < 8) ? (15 - g) : (g - 8);  // pair heavy+light per CU
  const int tid = threadIdx.x;
  const int lane = tid & 63;
  const int w = tid >> 6;
  const int l15 = lane & 15, l4 = lane >> 4;
  const int t0 = tile * 128;

  __shared__ __attribute__((aligned(16))) bf16 Es[64 * 128];   // q tile [s][h], swizzled
  __shared__ __attribute__((aligned(16))) bf16 Vs[128 * 64];   // Vt tile [h][s], swizzled
  __shared__ __attribute__((aligned(16))) bf16 Ps[4][32 * 72]; // wave-private P

  // k fragments (A operand) held in registers for whole kernel
  bf16x8 af[2][4];
  {
    const bf16* kp = kb + ((size_t)b * TT + t0 + w * 32 + l15) * HH + l4 * 8;
#pragma unroll
    for (int fm = 0; fm < 2; ++fm)
#pragma unroll
      for (int kc = 0; kc < 4; ++kc)
        af[fm][kc] = *(const bf16x8*)(kp + fm * 16 * HH + kc * 32);
  }

  f32x4 o[2][8];
#pragma unroll
  for (int i = 0; i < 2; ++i)
#pragma unroll
    for (int j = 0; j < 8; ++j) o[i][j] = f32x4{0.f, 0.f, 0.f, 0.f};
  float mrow[2][4], lrow[2][4];
#pragma unroll
  for (int i = 0; i < 2; ++i)
#pragma unroll
    for (int e = 0; e < 4; ++e) { mrow[i][e] = -3e38f; lrow[i][e] = 0.f; }

  const int nst = 2 * (tile + 1);
  for (int jt = 0; jt < nst; ++jt) {
    const int s0 = jt * 64;
    {
      const bf16* Eg = qb + ((size_t)b * TT + s0) * HH;    // [64][128]
#pragma unroll
      for (int it = 0; it < 4; ++it) {
        int L = w * 256 + it * 64 + lane;                  // chunk id
        int er = L >> 4, ec = L & 15;
        int ecs = ec ^ (er & 7);
        gl_lds16(Eg + er * HH + ecs * 8, Es + (size_t)(w * 256 + it * 64) * 8);
      }
      const bf16* Vg = Vt + (size_t)b * HH * TT + s0;      // rows h, 64 cols
#pragma unroll
      for (int it = 0; it < 4; ++it) {
        int L = w * 256 + it * 64 + lane;
        int vr = L >> 3, vc = L & 7;
        int vcs = vc ^ (vr & 7);
        gl_lds16(Vg + (size_t)vr * TT + vcs * 8, Vs + (size_t)(w * 256 + it * 64) * 8);
      }
    }
    __syncthreads();

    // S = k . q^T  (A=k frags, B from Es)
    f32x4 s[2][4];
#pragma unroll
    for (int i = 0; i < 2; ++i)
#pragma unroll
      for (int j = 0; j < 4; ++j) s[i][j] = f32x4{0.f, 0.f, 0.f, 0.f};
#pragma unroll
    for (int kc = 0; kc < 4; ++kc) {
      bf16x8 ef[4];
#pragma unroll
      for (int fn = 0; fn < 4; ++fn) {
        int er = fn * 16 + l15;
        int c = kc * 4 + l4;
        int cs = c ^ (er & 7);
        ef[fn] = *(const bf16x8*)&Es[er * 128 + cs * 8];
      }
#pragma unroll
      for (int fm = 0; fm < 2; ++fm)
#pragma unroll
        for (int fn = 0; fn < 4; ++fn)
          s[fm][fn] = __builtin_amdgcn_mfma_f32_16x16x32_bf16(af[fm][kc], ef[fn],
                                                              s[fm][fn], 0, 0, 0);
    }

    // scale + causal mask (s_glob > t_glob -> -inf)
    const bool needM = (s0 + 63 > t0 + w * 32);
#pragma unroll
    for (int fm = 0; fm < 2; ++fm)
#pragma unroll
      for (int fn = 0; fn < 4; ++fn)
#pragma unroll
        for (int e = 0; e < 4; ++e) {
          float v = s[fm][fn][e] * SCALE;
          if (needM) {
            int tg = t0 + w * 32 + fm * 16 + l4 * 4 + e;
            int sg = s0 + fn * 16 + l15;
            if (sg > tg) v = -3e38f;
          }
          s[fm][fn][e] = v;
        }

    // online softmax per row (rows live across the 16-lane l15 group)
#pragma unroll
    for (int fm = 0; fm < 2; ++fm)
#pragma unroll
      for (int e = 0; e < 4; ++e) {
        float mx = fmaxf(fmaxf(s[fm][0][e], s[fm][1][e]),
                         fmaxf(s[fm][2][e], s[fm][3][e]));
#pragma unroll
        for (int d = 1; d < 16; d <<= 1) mx = fmaxf(mx, __shfl_xor(mx, d));
        float mo = mrow[fm][e];
        float mn = fmaxf(mo, mx);
        mrow[fm][e] = mn;
        float rsc = exp2f((mo - mn) * LOG2E);
        lrow[fm][e] *= rsc;
#pragma unroll
        for (int fh = 0; fh < 8; ++fh) o[fm][fh][e] *= rsc;
        float ps = 0.f;
#pragma unroll
        for (int fn = 0; fn < 4; ++fn) {
          float p = exp2f((s[fm][fn][e] - mn) * LOG2E);
          s[fm][fn][e] = p;
          ps += p;
        }
#pragma unroll
        for (int d = 1; d < 16; d <<= 1) ps += __shfl_xor(ps, d);
        lrow[fm][e] += ps;
      }

    // P -> wave-private LDS (bf16), then PV MFMA
#pragma unroll
    for (int fm = 0; fm < 2; ++fm)
#pragma unroll
      for (int fn = 0; fn < 4; ++fn)
#pragma unroll
        for (int e = 0; e < 4; ++e)
          Ps[w][(fm * 16 + l4 * 4 + e) * 72 + fn * 16 + l15] = (bf16)s[fm][fn][e];

#pragma unroll
    for (int kc = 0; kc < 2; ++kc) {
      bf16x8 pf[2];
#pragma unroll
      for (int fm = 0; fm < 2; ++fm)
        pf[fm] = *(const bf16x8*)&Ps[w][(fm * 16 + l15) * 72 + kc * 32 + l4 * 8];
#pragma unroll
      for (int fh = 0; fh < 8; ++fh) {
        int vr = fh * 16 + l15;
        int c = kc * 4 + l4;
        int cs = c ^ (vr & 7);
        bf16x8 vf = *(const bf16x8*)&Vs[vr * 64 + cs * 8];
#pragma unroll
        for (int fm = 0; fm < 2; ++fm)
          o[fm][fh] = __builtin_amdgcn_mfma_f32_16x16x32_bf16(pf[fm], vf,
                                                              o[fm][fh], 0, 0, 0);
      }
    }
    __syncthreads();
  }

  // epilogue: O / l  -> fp32 out
#pragma unroll
  for (int fm = 0; fm < 2; ++fm)
#pragma unroll
    for (int e = 0; e < 4; ++e) {
      float rl = 1.0f / lrow[fm][e];
      int tg = t0 + w * 32 + fm * 16 + l4 * 4 + e;
#pragma unroll
      for (int fh = 0; fh < 8; ++fh)
        out[((size_t)b * TT + tg) * HH + fh * 16 + l15] = o[fm][fh][e] * rl;
    }
}

extern "C" void kernel_launch(void* const* d_in, const int* in_sizes, int n_in,
                              void* d_out, int out_size, void* d_ws, size_t ws_size,
                              hipStream_t stream) {
  (void)in_sizes; (void)n_in; (void)out_size; (void)ws_size;
  const float* x  = (const float*)d_in[0];
  const float* Wk = (const float*)d_in[1];
  const float* bk = (const float*)d_in[2];
  const float* Wq = (const float*)d_in[3];
  const float* bq = (const float*)d_in[4];
  const float* Wv = (const float*)d_in[5];
  const float* bv = (const float*)d_in[6];
  float* out = (float*)d_out;

  const size_t NTH = (size_t)BB * TT * HH;   // 8388608
  bf16* kb = (bf16*)d_ws;
  bf16* qb = kb + NTH;
  bf16* vb = qb + NTH;
  bf16* Vt = vb + NTH;
  bf16* Wt = Vt + NTH;                        // 3*128*1024

  prep_w<<<192, 256, 0, stream>>>(Wk, Wq, Wv, Wt);
  qkv_proj<<<512 * 3, 256, 0, stream>>>(x, Wt, bk, bq, bv, kb, qb, vb);
  transpose_v<<<BB * (TT / 128), 256, 0, stream>>>(vb, Vt);
  attn<<<512, 256, 0, stream>>>(kb, qb, Vt, out);
}

// Round 2
// 226.145 us; speedup vs baseline: 1.3085x; 1.3085x over previous
//
#include <hip/hip_runtime.h>
#include <hip/hip_bf16.h>
#include <stdint.h>

typedef __bf16 bf16;
typedef __bf16 bf16x8 __attribute__((ext_vector_type(8)));
typedef __bf16 bf16x4 __attribute__((ext_vector_type(4)));
typedef float f32x4 __attribute__((ext_vector_type(4)));

#define BB 32
#define TT 2048
#define DD 1024
#define HH 128
#define SCALE 0.08838834764831845f   // H^-0.5
#define LOG2E 1.4426950408889634f

__device__ __forceinline__ void gl_lds16(const bf16* g, bf16* l) {
  __builtin_amdgcn_global_load_lds((__attribute__((address_space(1))) const void*)g,
                                   (__attribute__((address_space(3))) void*)l,
                                   16, 0, 0);
}

// ---------------- kernel 0: Wt[mat][h][d] = W[d][h] (fp32 -> bf16) -------------
__global__ __launch_bounds__(256) void prep_w(const float* __restrict__ Wk,
                                              const float* __restrict__ Wq,
                                              const float* __restrict__ Wv,
                                              bf16* __restrict__ Wt) {
  int tid = blockIdx.x * 256 + threadIdx.x;   // 0..49151
  int mat = tid >> 14;
  int r = tid & 16383;
  int h = r & 127;
  int d0 = (r >> 7) << 3;
  const float* W = (mat == 0) ? Wk : (mat == 1) ? Wq : Wv;
  bf16x8 v;
#pragma unroll
  for (int i = 0; i < 8; ++i) v[i] = (bf16)W[(size_t)(d0 + i) * HH + h];
  *(bf16x8*)(Wt + ((size_t)mat * HH + h) * DD + d0) = v;
}

// ---------------- kernel 1: fused QKV projection GEMM (bf16 MFMA) --------------
// grid = 512 mtiles * 3 mats; block 256 = 4 waves (2x2), tile 128x128, BK=32
// k output pre-scaled by SCALE*LOG2E (softmax runs in exp2 domain).
// v output written directly transposed as Vt[b][h][t].
__global__ __launch_bounds__(256) void qkv_proj(
    const float* __restrict__ x, const bf16* __restrict__ Wt,
    const float* __restrict__ bk, const float* __restrict__ bq,
    const float* __restrict__ bv,
    bf16* __restrict__ kb, bf16* __restrict__ qb, bf16* __restrict__ Vt) {
  const int bid = blockIdx.x;
  const int mat = bid % 3;
  const int mtile = bid / 3;
  const int tid = threadIdx.x;
  const int lane = tid & 63;
  const int w = tid >> 6;
  const int wr = w >> 1, wc = w & 1;
  const int l15 = lane & 15, l4 = lane >> 4;

  __shared__ __attribute__((aligned(16))) bf16 As[2][128][40];
  __shared__ __attribute__((aligned(16))) bf16 Bs[2][128][40];

  const size_t row0 = (size_t)mtile * 128;
  const bf16* Wm = Wt + (size_t)mat * HH * DD;
  const float* bias = (mat == 0) ? bk : (mat == 1) ? bq : bv;

  const int ar = tid >> 3, ac = (tid & 7) * 4;   // A stage: 8 thr/row
  const int br = tid >> 2, bc = (tid & 3) * 8;   // B stage: 4 thr/row

  f32x4 acc[4][4];
#pragma unroll
  for (int i = 0; i < 4; ++i)
#pragma unroll
    for (int j = 0; j < 4; ++j) acc[i][j] = f32x4{0.f, 0.f, 0.f, 0.f};

  auto stage = [&](int buf, int k0) {
#pragma unroll
    for (int p = 0; p < 4; ++p) {
      int r = p * 32 + ar;
      f32x4 a = *(const f32x4*)(x + (row0 + r) * DD + k0 + ac);
      bf16x4 t;
#pragma unroll
      for (int i = 0; i < 4; ++i) t[i] = (bf16)a[i];
      *(bf16x4*)&As[buf][r][ac] = t;
    }
#pragma unroll
    for (int p = 0; p < 2; ++p) {
      int r = p * 64 + br;
      bf16x8 bv8 = *(const bf16x8*)(Wm + (size_t)r * DD + k0 + bc);
      *(bf16x8*)&Bs[buf][r][bc] = bv8;
    }
  };

  stage(0, 0);
  __syncthreads();

  for (int k0 = 0; k0 < DD; k0 += 32) {
    const int cur = (k0 >> 5) & 1;
    if (k0 + 32 < DD) stage(cur ^ 1, k0 + 32);

    bf16x8 af[4], bfr[4];
#pragma unroll
    for (int f = 0; f < 4; ++f)
      af[f] = *(const bf16x8*)&As[cur][wr * 64 + f * 16 + l15][l4 * 8];
#pragma unroll
    for (int f = 0; f < 4; ++f)
      bfr[f] = *(const bf16x8*)&Bs[cur][wc * 64 + f * 16 + l15][l4 * 8];
#pragma unroll
    for (int i = 0; i < 4; ++i)
#pragma unroll
      for (int j = 0; j < 4; ++j)
        acc[i][j] = __builtin_amdgcn_mfma_f32_16x16x32_bf16(af[i], bfr[j],
                                                            acc[i][j], 0, 0, 0);
    __syncthreads();
  }

  float bvv[4];
#pragma unroll
  for (int f = 0; f < 4; ++f) bvv[f] = bias[wc * 64 + f * 16 + l15];

  if (mat == 2) {
    // write Vt[b][h][t] directly (bf16x4 = 4 contiguous t per lane)
    const int bidx = mtile >> 4;
    const int tbase = (mtile & 15) * 128;
#pragma unroll
    for (int i = 0; i < 4; ++i)
#pragma unroll
      for (int j = 0; j < 4; ++j) {
        int col = wc * 64 + j * 16 + l15;
        bf16x4 v4;
#pragma unroll
        for (int e = 0; e < 4; ++e) v4[e] = (bf16)(acc[i][j][e] + bvv[j]);
        int t = tbase + wr * 64 + i * 16 + l4 * 4;
        *(bf16x4*)(Vt + ((size_t)bidx * HH + col) * TT + t) = v4;
      }
  } else {
    const float ks = (mat == 0) ? (SCALE * LOG2E) : 1.0f;
    bf16* outp = (mat == 0) ? kb : qb;
#pragma unroll
    for (int i = 0; i < 4; ++i)
#pragma unroll
      for (int j = 0; j < 4; ++j) {
        int col = wc * 64 + j * 16 + l15;
#pragma unroll
        for (int e = 0; e < 4; ++e) {
          int row = wr * 64 + i * 16 + l4 * 4 + e;
          outp[(row0 + row) * HH + col] = (bf16)((acc[i][j][e] + bvv[j]) * ks);
        }
      }
  }
}

// ---------------- kernel 2: fused causal flash attention -----------------------
// quirk: scores[t][s] = k[t].q[s] -> k rows are the softmax rows (k pre-scaled
// by SCALE*LOG2E, so softmax is computed with exp2 directly).
// grid 512; block 256 = 4 waves * 16 rows = 64-row t-tile.
// Each block runs TWO complementary jobs: tiles (31-p) and (p) -> exactly
// 33 s-iterations per block (perfect balance), all 512 blocks co-resident
// (LDS 41 KB -> 3 blocks/CU).
__global__ __launch_bounds__(256, 3) void attn(const bf16* __restrict__ kb,
                                               const bf16* __restrict__ qb,
                                               const bf16* __restrict__ Vt,
                                               float* __restrict__ out) {
  const int bid = blockIdx.x;
  const int b = bid & 31;
  const int p = bid >> 5;                 // 0..15
  const int tid = threadIdx.x;
  const int lane = tid & 63;
  const int w = tid >> 6;
  const int l15 = lane & 15, l4 = lane >> 4;

  __shared__ __attribute__((aligned(16))) bf16 Es[64 * 128];   // q tile [s][h], swizzled
  __shared__ __attribute__((aligned(16))) bf16 Vs[128 * 64];   // Vt tile [h][s], swizzled
  __shared__ __attribute__((aligned(16))) bf16 Ps[4][16 * 72]; // wave-private P

  for (int job = 0; job < 2; ++job) {
    const int tile = job ? p : (31 - p);
    const int t0 = tile * 64;

    // k fragments (A operand, 16 rows per wave) in registers
    bf16x8 af[4];
    {
      const bf16* kp = kb + ((size_t)b * TT + t0 + w * 16 + l15) * HH + l4 * 8;
#pragma unroll
      for (int kc = 0; kc < 4; ++kc) af[kc] = *(const bf16x8*)(kp + kc * 32);
    }

    f32x4 o[8];
#pragma unroll
    for (int j = 0; j < 8; ++j) o[j] = f32x4{0.f, 0.f, 0.f, 0.f};
    float mrow[4], lrow[4];
#pragma unroll
    for (int e = 0; e < 4; ++e) { mrow[e] = -1e30f; lrow[e] = 0.f; }

    const int nst = tile + 1;
    for (int jt = 0; jt < nst; ++jt) {
      const int s0 = jt * 64;
      {
        const bf16* Eg = qb + ((size_t)b * TT + s0) * HH;      // [64][128]
#pragma unroll
        for (int it = 0; it < 4; ++it) {
          int L = w * 256 + it * 64 + lane;                    // chunk id
          int er = L >> 4, ec = L & 15;
          int ecs = ec ^ (er & 7);
          gl_lds16(Eg + er * HH + ecs * 8, Es + (size_t)(w * 256 + it * 64) * 8);
        }
        const bf16* Vg = Vt + (size_t)b * HH * TT + s0;        // rows h, 64 cols
#pragma unroll
        for (int it = 0; it < 4; ++it) {
          int L = w * 256 + it * 64 + lane;
          int vr = L >> 3, vc = L & 7;
          int vcs = vc ^ (vr & 7);
          gl_lds16(Vg + (size_t)vr * TT + vcs * 8, Vs + (size_t)(w * 256 + it * 64) * 8);
        }
      }
      __syncthreads();

      // S = k . q^T   (already in exp2/log2 domain via pre-scaled k)
      f32x4 s[4];
#pragma unroll
      for (int j = 0; j < 4; ++j) s[j] = f32x4{0.f, 0.f, 0.f, 0.f};
#pragma unroll
      for (int kc = 0; kc < 4; ++kc) {
        bf16x8 ef[4];
#pragma unroll
        for (int fn = 0; fn < 4; ++fn) {
          int er = fn * 16 + l15;
          int c = kc * 4 + l4;
          int cs = c ^ (er & 7);
          ef[fn] = *(const bf16x8*)&Es[er * 128 + cs * 8];
        }
#pragma unroll
        for (int fn = 0; fn < 4; ++fn)
          s[fn] = __builtin_amdgcn_mfma_f32_16x16x32_bf16(af[kc], ef[fn],
                                                          s[fn], 0, 0, 0);
      }

      // causal mask (s_glob > t_glob -> -inf)
      if (s0 + 63 > t0 + w * 16) {
#pragma unroll
        for (int fn = 0; fn < 4; ++fn)
#pragma unroll
          for (int e = 0; e < 4; ++e) {
            int tg = t0 + w * 16 + l4 * 4 + e;
            int sg = s0 + fn * 16 + l15;
            if (sg > tg) s[fn][e] = -1e30f;
          }
      }

      // online softmax (log2 domain), defer-max rescale (threshold 8)
      float mx[4];
#pragma unroll
      for (int e = 0; e < 4; ++e) {
        float m = fmaxf(fmaxf(s[0][e], s[1][e]), fmaxf(s[2][e], s[3][e]));
#pragma unroll
        for (int d = 1; d < 16; d <<= 1) m = fmaxf(m, __shfl_xor(m, d));
        mx[e] = m;
      }
      float g = fmaxf(fmaxf(mx[0] - mrow[0], mx[1] - mrow[1]),
                      fmaxf(mx[2] - mrow[2], mx[3] - mrow[3]));
      if (!__all(g <= 8.0f)) {
#pragma unroll
        for (int e = 0; e < 4; ++e) {
          float mn = fmaxf(mrow[e], mx[e]);
          float rsc = exp2f(mrow[e] - mn);
          lrow[e] *= rsc;
#pragma unroll
          for (int fh = 0; fh < 8; ++fh) o[fh][e] *= rsc;
          mrow[e] = mn;
        }
      }
#pragma unroll
      for (int e = 0; e < 4; ++e) {
        float ps = 0.f;
#pragma unroll
        for (int fn = 0; fn < 4; ++fn) {
          float pv = exp2f(s[fn][e] - mrow[e]);
          s[fn][e] = pv;
          ps += pv;
        }
#pragma unroll
        for (int d = 1; d < 16; d <<= 1) ps += __shfl_xor(ps, d);
        lrow[e] += ps;
      }

      // P -> wave-private LDS (bf16), then PV MFMA
#pragma unroll
      for (int fn = 0; fn < 4; ++fn)
#pragma unroll
        for (int e = 0; e < 4; ++e)
          Ps[w][(l4 * 4 + e) * 72 + fn * 16 + l15] = (bf16)s[fn][e];

#pragma unroll
      for (int kc = 0; kc < 2; ++kc) {
        bf16x8 pf = *(const bf16x8*)&Ps[w][l15 * 72 + kc * 32 + l4 * 8];
#pragma unroll
        for (int fh = 0; fh < 8; ++fh) {
          int vr = fh * 16 + l15;
          int c = kc * 4 + l4;
          int cs = c ^ (vr & 7);
          bf16x8 vf = *(const bf16x8*)&Vs[vr * 64 + cs * 8];
          o[fh] = __builtin_amdgcn_mfma_f32_16x16x32_bf16(pf, vf, o[fh], 0, 0, 0);
        }
      }
      __syncthreads();
    }

    // epilogue: O / l -> fp32 out
#pragma unroll
    for (int e = 0; e < 4; ++e) {
      float rl = 1.0f / lrow[e];
      int tg = t0 + w * 16 + l4 * 4 + e;
#pragma unroll
      for (int fh = 0; fh < 8; ++fh)
        out[((size_t)b * TT + tg) * HH + fh * 16 + l15] = o[fh][e] * rl;
    }
  }
}

extern "C" void kernel_launch(void* const* d_in, const int* in_sizes, int n_in,
                              void* d_out, int out_size, void* d_ws, size_t ws_size,
                              hipStream_t stream) {
  (void)in_sizes; (void)n_in; (void)out_size; (void)ws_size;
  const float* x  = (const float*)d_in[0];
  const float* Wk = (const float*)d_in[1];
  const float* bk = (const float*)d_in[2];
  const float* Wq = (const float*)d_in[3];
  const float* bq = (const float*)d_in[4];
  const float* Wv = (const float*)d_in[5];
  const float* bv = (const float*)d_in[6];
  float* out = (float*)d_out;

  const size_t NTH = (size_t)BB * TT * HH;   // 8388608
  bf16* kb = (bf16*)d_ws;
  bf16* qb = kb + NTH;
  bf16* Vt = qb + NTH;
  bf16* Wt = Vt + NTH;                        // 3*128*1024

  prep_w<<<192, 256, 0, stream>>>(Wk, Wq, Wv, Wt);
  qkv_proj<<<512 * 3, 256, 0, stream>>>(x, Wt, bk, bq, bv, kb, qb, Vt);
  attn<<<512, 256, 0, stream>>>(kb, qb, Vt, out);
}